// Round 7
// baseline (489.937 us; speedup 1.0000x reference)
//
#include <hip/hip_runtime.h>
#include <cstddef>

#define BN 2
#define NN 20000
#define NE 400000
#define HH 128

typedef __attribute__((ext_vector_type(8))) short bf16x8;
typedef __attribute__((ext_vector_type(4))) float f32x4;
typedef unsigned short ushort_t;

__device__ __forceinline__ unsigned short f2b(float f) {
    unsigned u = __float_as_uint(f);
    unsigned r = (u + 0x7FFFu + ((u >> 16) & 1u)) >> 16;
    return (unsigned short)r;
}
__device__ __forceinline__ float b2f(ushort_t v) {
    return __uint_as_float(((unsigned)v) << 16);
}

__device__ __forceinline__ void gll16(const void* g, void* l) {
    __builtin_amdgcn_global_load_lds(
        (const __attribute__((address_space(1))) unsigned int*)g,
        (__attribute__((address_space(3))) unsigned int*)l,
        16, 0, 0);
}

// ---------------------------------------------------------------------------
// prep: h (fp32) -> bf16
// ---------------------------------------------------------------------------
__global__ void cvt_h_kernel(const float4* __restrict__ src, uint2* __restrict__ dst, int n4) {
    int i = blockIdx.x * 256 + threadIdx.x;
    if (i >= n4) return;
    float4 v = src[i];
    uint2 o;
    o.x = (unsigned)f2b(v.x) | ((unsigned)f2b(v.y) << 16);
    o.y = (unsigned)f2b(v.z) | ((unsigned)f2b(v.w) << 16);
    dst[i] = o;
}

// ---------------------------------------------------------------------------
// prep: pack W[K][128] fp32 -> fragment-order bf16 (same bijection as A path)
// ---------------------------------------------------------------------------
__global__ void pack_w_kernel(const float* __restrict__ W, ushort_t* __restrict__ dst, int K) {
    int slot = blockIdx.x * 256 + threadIdx.x;
    int total = (K >> 6) * 1024;
    if (slot >= total) return;
    int l = slot & 63, nt = (slot >> 6) & 7, kt2 = (slot >> 9) & 1, c = slot >> 10;
    int col = nt * 16 + (l & 15);
    int k0 = c * 64 + kt2 * 32 + ((l >> 4) * 8);
    unsigned out[4];
    #pragma unroll
    for (int p = 0; p < 4; ++p) {
        unsigned lo = f2b(W[(size_t)(k0 + 2 * p) * HH + col]);
        unsigned hi = f2b(W[(size_t)(k0 + 2 * p + 1) * HH + col]);
        out[p] = lo | (hi << 16);
    }
    uint4* d = (uint4*)&dst[(size_t)slot * 8];
    *d = make_uint4(out[0], out[1], out[2], out[3]);
}

// ---------------------------------------------------------------------------
// counting sort by row: hist -> scan -> scatter (materializes rowS/colS)
// ---------------------------------------------------------------------------
__global__ void hist_kernel(const int* __restrict__ eidx, int* __restrict__ histI) {
    int e = blockIdx.x * 256 + threadIdx.x;
    if (e >= NE) return;
    atomicAdd(&histI[eidx[e]], 1);
}

__global__ void scan_kernel(const int* __restrict__ histI, int* __restrict__ cursor,
                            float* __restrict__ cnt) {
    __shared__ int part[256];
    const int t = threadIdx.x;
    const int chunk = (NN + 255) / 256;
    const int lo = t * chunk, hi = min(lo + chunk, NN);
    int s = 0;
    for (int i = lo; i < hi; ++i) s += histI[i];
    part[t] = s;
    __syncthreads();
    for (int d = 1; d < 256; d <<= 1) {
        int v = (t >= d) ? part[t - d] : 0;
        __syncthreads();
        part[t] += v;
        __syncthreads();
    }
    int run = part[t] - s;   // exclusive prefix
    for (int i = lo; i < hi; ++i) {
        cursor[i] = run;
        int hv = histI[i];
        cnt[i] = (float)hv;
        run += hv;
    }
}

__global__ void scatter_kernel(const int* __restrict__ eidx, int* __restrict__ cursor,
                               int* __restrict__ rowS, int* __restrict__ colS) {
    int e = blockIdx.x * 256 + threadIdx.x;
    if (e >= NE) return;
    const int r = eidx[e];
    int p = atomicAdd(&cursor[r], 1);
    rowS[p] = r;
    colS[p] = eidx[NE + e];
}

// ===========================================================================
// Edge kernel: 128 sorted edges/block, XCD-chunked block swizzle,
// weights in VGPRs, FA/YN LDS overlay (4 blocks/CU).
// ===========================================================================
#define MFMA_FA(BB)                                                               \
    _Pragma("unroll")                                                             \
    for (int ktg = 0; ktg < 4; ++ktg) {                                           \
        _Pragma("unroll")                                                         \
        for (int mt = 0; mt < 8; ++mt) {                                          \
            bf16x8 a = *(const bf16x8*)&FA[((ktg * 8 + mt) * 64 + l) * 8];        \
            acc[mt][0] = __builtin_amdgcn_mfma_f32_16x16x32_bf16(                 \
                a, bw[(BB) + ktg * 2 + 0], acc[mt][0], 0, 0, 0);                  \
            acc[mt][1] = __builtin_amdgcn_mfma_f32_16x16x32_bf16(                 \
                a, bw[(BB) + ktg * 2 + 1], acc[mt][1], 0, 0, 0);                  \
        }                                                                         \
    }

#define MFMA_YN(BB)                                                               \
    _Pragma("unroll")                                                             \
    for (int ktg = 0; ktg < 4; ++ktg) {                                           \
        _Pragma("unroll")                                                         \
        for (int mt = 0; mt < 8; ++mt) {                                          \
            const int row_ = mt * 16 + lo16;                                      \
            bf16x8 a = *(const bf16x8*)&YN[row_ * 136 + ktg * 32 + hi4 * 8];      \
            acc[mt][0] = __builtin_amdgcn_mfma_f32_16x16x32_bf16(                 \
                a, bw[(BB) + ktg * 2 + 0], acc[mt][0], 0, 0, 0);                  \
            acc[mt][1] = __builtin_amdgcn_mfma_f32_16x16x32_bf16(                 \
                a, bw[(BB) + ktg * 2 + 1], acc[mt][1], 0, 0, 0);                  \
        }                                                                         \
    }

__global__ __launch_bounds__(256, 4)
void edge_kernel(const ushort_t* __restrict__ hbf, const float* __restrict__ coord,
                 const int* __restrict__ rowS, const int* __restrict__ colS,
                 const ushort_t* __restrict__ w1p, const ushort_t* __restrict__ w2p,
                 const ushort_t* __restrict__ cw1p,
                 const float* __restrict__ w1, const float* __restrict__ b1,
                 const float* __restrict__ b2, const float* __restrict__ cb1,
                 const float* __restrict__ cw2,
                 float* __restrict__ agg, float* __restrict__ aggt)
{
    __shared__ ushort_t SH[128 * 136];        // 34.8 KB — FA (16384) / YN overlay
    __shared__ int Rw[129], Cw[128];
    __shared__ float CD3[128 * 3];
    __shared__ float Rad[128];
    __shared__ float GT[128];

    ushort_t* const FA = SH;
    ushort_t* const YN = SH;

    const int t = threadIdx.x;
    const int l = t & 63;
    const int w = t >> 6;
    const int b = blockIdx.y;

    // XCD-chunked bijective swizzle (m204): consecutive sorted tiles -> same XCD
    // so shared agg-rows / h-rows stay in one XCD's L2.
    const int nwg = gridDim.x;
    const int q = nwg >> 3, r8 = nwg & 7;
    const int xcd = blockIdx.x & 7, pos = blockIdx.x >> 3;
    const int tile = (xcd < r8 ? xcd * (q + 1) : r8 * (q + 1) + (xcd - r8) * q) + pos;
    const int e0 = tile * 128;

    const int lo16 = l & 15;
    const int hi4 = l >> 4;
    const int col0 = w * 32 + lo16;
    const int col1 = col0 + 16;

    // w1 B-fragments -> 64 VGPRs
    bf16x8 bw[16];
    #pragma unroll
    for (int ktg = 0; ktg < 8; ++ktg) {
        bw[ktg * 2 + 0] = *(const bf16x8*)&w1p[((ktg * 8 + w * 2 + 0) * 64 + l) * 8];
        bw[ktg * 2 + 1] = *(const bf16x8*)&w1p[((ktg * 8 + w * 2 + 1) * 64 + l) * 8];
    }

    if (t < 128) {
        int r = rowS[e0 + t], c = colS[e0 + t];
        Rw[t] = r; Cw[t] = c; GT[t] = 0.0f;
        if (t == 0) Rw[128] = -1;
        const float* cr = coord + ((size_t)b * NN + r) * 3;
        const float* cc = coord + ((size_t)b * NN + c) * 3;
        float d0 = cr[0] - cc[0], d1 = cr[1] - cc[1], d2 = cr[2] - cc[2];
        CD3[t * 3] = d0; CD3[t * 3 + 1] = d1; CD3[t * 3 + 2] = d2;
        Rad[t] = d0 * d0 + d1 * d1 + d2 * d2;
    }

    f32x4 acc[8][2];
    #pragma unroll
    for (int mt = 0; mt < 8; ++mt) { acc[mt][0] = (f32x4)0.0f; acc[mt][1] = (f32x4)0.0f; }

    __syncthreads();   // Rw/Cw visible

    // ---- stage A row-half (K=128) ----
    #pragma unroll
    for (int i = 0; i < 2; ++i) {
        const int mt = w * 2 + i;
        const ushort_t* hb = hbf + ((size_t)b * NN + Rw[mt * 16 + lo16]) * HH + hi4 * 8;
        #pragma unroll
        for (int ktg = 0; ktg < 4; ++ktg)
            gll16(hb + ktg * 32, (void*)&FA[((ktg * 8 + mt) * 64) * 8]);
    }
    __syncthreads();

    MFMA_FA(0)         // L1, k 0..127
    __syncthreads();

    // ---- stage A col-half ----
    #pragma unroll
    for (int i = 0; i < 2; ++i) {
        const int mt = w * 2 + i;
        const ushort_t* hb = hbf + ((size_t)b * NN + Cw[mt * 16 + lo16]) * HH + hi4 * 8;
        #pragma unroll
        for (int ktg = 0; ktg < 4; ++ktg)
            gll16(hb + ktg * 32, (void*)&FA[((ktg * 8 + mt) * 64) * 8]);
    }
    __syncthreads();

    MFMA_FA(8)         // L1, k 128..255

    // reuse B regs: w2 -> bw[0..7], cw1 -> bw[8..15]
    #pragma unroll
    for (int ktg = 0; ktg < 4; ++ktg) {
        bw[ktg * 2 + 0] = *(const bf16x8*)&w2p[((ktg * 8 + w * 2 + 0) * 64 + l) * 8];
        bw[ktg * 2 + 1] = *(const bf16x8*)&w2p[((ktg * 8 + w * 2 + 1) * 64 + l) * 8];
        bw[8 + ktg * 2 + 0] = *(const bf16x8*)&cw1p[((ktg * 8 + w * 2 + 0) * 64 + l) * 8];
        bw[8 + ktg * 2 + 1] = *(const bf16x8*)&cw1p[((ktg * 8 + w * 2 + 1) * 64 + l) * 8];
    }

    __syncthreads();   // WAR: all FA readers done before YN overwrite (overlay)

    // ---- epilogue 1: radial + bias + relu -> YN ----
    {
        const float w1r0 = w1[256 * HH + col0];
        const float w1r1 = w1[256 * HH + col1];
        const float b10 = b1[col0], b11 = b1[col1];
        #pragma unroll
        for (int mt = 0; mt < 8; ++mt)
            #pragma unroll
            for (int j = 0; j < 4; ++j) {
                const int row = mt * 16 + hi4 * 4 + j;
                const float r = Rad[row];
                float v0 = fmaxf(acc[mt][0][j] + r * w1r0 + b10, 0.0f);
                float v1 = fmaxf(acc[mt][1][j] + r * w1r1 + b11, 0.0f);
                YN[row * 136 + col0] = f2b(v0);
                YN[row * 136 + col1] = f2b(v1);
                acc[mt][0][j] = 0.0f; acc[mt][1][j] = 0.0f;
            }
    }
    __syncthreads();

    MFMA_YN(0)         // L2: feat = y1 @ w2
    __syncthreads();

    // ---- feat epilogue: relu -> YN ----
    {
        const float b20 = b2[col0], b21 = b2[col1];
        #pragma unroll
        for (int mt = 0; mt < 8; ++mt)
            #pragma unroll
            for (int j = 0; j < 4; ++j) {
                const int row = mt * 16 + hi4 * 4 + j;
                float v0 = fmaxf(acc[mt][0][j] + b20, 0.0f);
                float v1 = fmaxf(acc[mt][1][j] + b21, 0.0f);
                YN[row * 136 + col0] = f2b(v0);
                YN[row * 136 + col1] = f2b(v1);
                acc[mt][0][j] = 0.0f; acc[mt][1][j] = 0.0f;
            }
    }
    __syncthreads();   // YN (feat) complete for all waves

    MFMA_YN(8)         // L3: g1 = feat @ cw1

    // ---- agg segment scan: one atomic per (row-run, col) ----
    {
        const int colc = t & 127;
        const int half = t >> 7;
        const int r0 = half * 64;
        float s = 0.0f;
        for (int r = r0; r < r0 + 64; ++r) {
            s += b2f(YN[r * 136 + colc]);
            if (r == r0 + 63 || Rw[r] != Rw[r + 1]) {   // wave-uniform flush
                atomicAdd(&agg[((size_t)b * NN + Rw[r]) * HH + colc], s);
                s = 0.0f;
            }
        }
    }

    // ---- gate epilogue ----
    {
        const float cbA = cb1[col0], cbB = cb1[col1];
        const float cwA = cw2[col0], cwB = cw2[col1];
        #pragma unroll
        for (int mt = 0; mt < 8; ++mt)
            #pragma unroll
            for (int j = 0; j < 4; ++j) {
                float g = fmaxf(acc[mt][0][j] + cbA, 0.0f) * cwA
                        + fmaxf(acc[mt][1][j] + cbB, 0.0f) * cwB;
                g += __shfl_xor(g, 1);
                g += __shfl_xor(g, 2);
                g += __shfl_xor(g, 4);
                g += __shfl_xor(g, 8);
                if (lo16 == 0)
                    atomicAdd(&GT[mt * 16 + hi4 * 4 + j], g);
            }
    }
    __syncthreads();

    // ---- aggt run-reduce: run-head sums its run, 3 atomics per run ----
    if (t < 128) {
        const bool head = (t == 0) || (Rw[t] != Rw[t - 1]);
        if (head) {
            float s0 = 0.0f, s1 = 0.0f, s2 = 0.0f;
            int r = t;
            const int myrow = Rw[t];
            while (r < 128 && Rw[r] == myrow) {
                const float g = GT[r];
                s0 += CD3[r * 3 + 0] * g;
                s1 += CD3[r * 3 + 1] * g;
                s2 += CD3[r * 3 + 2] * g;
                ++r;
            }
            const size_t base = ((size_t)b * NN + myrow) * 3;
            atomicAdd(&aggt[base + 0], s0);
            atomicAdd(&aggt[base + 1], s1);
            atomicAdd(&aggt[base + 2], s2);
        }
    }
}

// ===========================================================================
// Node kernel: 64 nodes/block (2x blocks vs r6 for occupancy), MFMA,
// nw1 (K=384) in 96 VGPRs, FA/YN overlay (~18 KB LDS).
// ===========================================================================
#define MFMA_FA4(BB)                                                              \
    _Pragma("unroll")                                                             \
    for (int ktg = 0; ktg < 4; ++ktg) {                                           \
        _Pragma("unroll")                                                         \
        for (int mt = 0; mt < 4; ++mt) {                                          \
            bf16x8 a = *(const bf16x8*)&FA[((ktg * 4 + mt) * 64 + l) * 8];        \
            acc[mt][0] = __builtin_amdgcn_mfma_f32_16x16x32_bf16(                 \
                a, bw[(BB) + ktg * 2 + 0], acc[mt][0], 0, 0, 0);                  \
            acc[mt][1] = __builtin_amdgcn_mfma_f32_16x16x32_bf16(                 \
                a, bw[(BB) + ktg * 2 + 1], acc[mt][1], 0, 0, 0);                  \
        }                                                                         \
    }

#define MFMA_YN4(BB)                                                              \
    _Pragma("unroll")                                                             \
    for (int ktg = 0; ktg < 4; ++ktg) {                                           \
        _Pragma("unroll")                                                         \
        for (int mt = 0; mt < 4; ++mt) {                                          \
            const int row_ = mt * 16 + lo16;                                      \
            bf16x8 a = *(const bf16x8*)&YN[row_ * 136 + ktg * 32 + hi4 * 8];      \
            acc[mt][0] = __builtin_amdgcn_mfma_f32_16x16x32_bf16(                 \
                a, bw[(BB) + ktg * 2 + 0], acc[mt][0], 0, 0, 0);                  \
            acc[mt][1] = __builtin_amdgcn_mfma_f32_16x16x32_bf16(                 \
                a, bw[(BB) + ktg * 2 + 1], acc[mt][1], 0, 0, 0);                  \
        }                                                                         \
    }

__global__ __launch_bounds__(256, 2)
void node_kernel(const ushort_t* __restrict__ hbf, const float* __restrict__ h,
                 const float* __restrict__ coord, const float* __restrict__ others,
                 const float* __restrict__ agg,
                 const ushort_t* __restrict__ nw1p, const ushort_t* __restrict__ nw2p,
                 const float* __restrict__ nb1, const float* __restrict__ nb2,
                 const float* __restrict__ aggt, const float* __restrict__ cnt,
                 float* __restrict__ out)
{
    __shared__ ushort_t SH[64 * 136];         // FA (8192) / YN overlay, ~17.4 KB
    ushort_t* const FA = SH;
    ushort_t* const YN = SH;

    const int t = threadIdx.x;
    const int l = t & 63;
    const int w = t >> 6;
    const int b = blockIdx.y;
    const int n0 = blockIdx.x * 64;

    const int lo16 = l & 15;
    const int hi4 = l >> 4;
    const int col0 = w * 32 + lo16;
    const int col1 = col0 + 16;

    bf16x8 bw[24];
    #pragma unroll
    for (int ktg = 0; ktg < 12; ++ktg) {
        bw[ktg * 2 + 0] = *(const bf16x8*)&nw1p[((ktg * 8 + w * 2 + 0) * 64 + l) * 8];
        bw[ktg * 2 + 1] = *(const bf16x8*)&nw1p[((ktg * 8 + w * 2 + 1) * 64 + l) * 8];
    }

    if (t < 64) {
        const int n = n0 + t;
        if (n < NN) {
            const float rinv = 1.0f / fmaxf(cnt[n], 1.0f);
            const float* cp = coord + ((size_t)b * NN + n) * 3;
            const float* ap = aggt + ((size_t)b * NN + n) * 3;
            float* op = out + ((size_t)b * NN + n) * 131 + HH;
            op[0] = cp[0] + ap[0] * rinv;
            op[1] = cp[1] + ap[1] * rinv;
            op[2] = cp[2] + ap[2] * rinv;
        }
    }

    f32x4 acc[4][2];
    #pragma unroll
    for (int mt = 0; mt < 4; ++mt) { acc[mt][0] = (f32x4)0.0f; acc[mt][1] = (f32x4)0.0f; }

    // fp32 source -> bf16 frag-order LDS staging; wave w stages mt=w
    #define STAGE_CVT(SRC)                                                        \
        {                                                                         \
            const int mt = w;                                                     \
            const int row = min(n0 + mt * 16 + lo16, NN - 1);                     \
            const float* p = (SRC) + ((size_t)b * NN + row) * HH + hi4 * 8;       \
            _Pragma("unroll")                                                     \
            for (int ktg = 0; ktg < 4; ++ktg) {                                   \
                float4 fa = *(const float4*)(p + ktg * 32);                       \
                float4 fb = *(const float4*)(p + ktg * 32 + 4);                   \
                uint4 u;                                                          \
                u.x = (unsigned)f2b(fa.x) | ((unsigned)f2b(fa.y) << 16);          \
                u.y = (unsigned)f2b(fa.z) | ((unsigned)f2b(fa.w) << 16);          \
                u.z = (unsigned)f2b(fb.x) | ((unsigned)f2b(fb.y) << 16);          \
                u.w = (unsigned)f2b(fb.z) | ((unsigned)f2b(fb.w) << 16);          \
                *(uint4*)&FA[((ktg * 4 + mt) * 64 + l) * 8] = u;                  \
            }                                                                     \
        }

    STAGE_CVT(others)
    __syncthreads();
    MFMA_FA4(0)
    __syncthreads();

    {
        const int mt = w;
        const int row = min(n0 + mt * 16 + lo16, NN - 1);
        const ushort_t* hb = hbf + ((size_t)b * NN + row) * HH + hi4 * 8;
        #pragma unroll
        for (int ktg = 0; ktg < 4; ++ktg)
            gll16(hb + ktg * 32, (void*)&FA[((ktg * 4 + mt) * 64) * 8]);
    }
    __syncthreads();
    MFMA_FA4(8)
    __syncthreads();

    STAGE_CVT(agg)
    __syncthreads();
    MFMA_FA4(16)

    #pragma unroll
    for (int ktg = 0; ktg < 4; ++ktg) {
        bw[ktg * 2 + 0] = *(const bf16x8*)&nw2p[((ktg * 8 + w * 2 + 0) * 64 + l) * 8];
        bw[ktg * 2 + 1] = *(const bf16x8*)&nw2p[((ktg * 8 + w * 2 + 1) * 64 + l) * 8];
    }

    __syncthreads();   // WAR: FA readers done before YN overwrite (overlay)

    {
        const float b10 = nb1[col0], b11 = nb1[col1];
        #pragma unroll
        for (int mt = 0; mt < 4; ++mt)
            #pragma unroll
            for (int j = 0; j < 4; ++j) {
                const int row = mt * 16 + hi4 * 4 + j;
                float v0 = fmaxf(acc[mt][0][j] + b10, 0.0f);
                float v1 = fmaxf(acc[mt][1][j] + b11, 0.0f);
                YN[row * 136 + col0] = f2b(v0);
                YN[row * 136 + col1] = f2b(v1);
                acc[mt][0][j] = 0.0f; acc[mt][1][j] = 0.0f;
            }
    }
    __syncthreads();

    MFMA_YN4(0)

    {
        const float b20 = nb2[col0], b21 = nb2[col1];
        #pragma unroll
        for (int mt = 0; mt < 4; ++mt)
            #pragma unroll
            for (int j = 0; j < 4; ++j) {
                const int rowg = n0 + mt * 16 + hi4 * 4 + j;
                if (rowg < NN) {
                    const size_t rb = (size_t)b * NN + rowg;
                    out[rb * 131 + col0] = h[rb * HH + col0] + acc[mt][0][j] + b20;
                    out[rb * 131 + col1] = h[rb * HH + col1] + acc[mt][1][j] + b21;
                }
            }
    }
}

extern "C" void kernel_launch(void* const* d_in, const int* in_sizes, int n_in,
                              void* d_out, int out_size, void* d_ws, size_t ws_size,
                              hipStream_t stream)
{
    const float* h      = (const float*)d_in[0];
    const float* coord  = (const float*)d_in[1];
    const float* others = (const float*)d_in[2];
    const int*   eidx   = (const int*)d_in[3];
    const float* w1  = (const float*)d_in[4];
    const float* b1  = (const float*)d_in[5];
    const float* w2  = (const float*)d_in[6];
    const float* b2  = (const float*)d_in[7];
    const float* nw1 = (const float*)d_in[8];
    const float* nb1 = (const float*)d_in[9];
    const float* nw2 = (const float*)d_in[10];
    const float* nb2 = (const float*)d_in[11];
    const float* cw1 = (const float*)d_in[12];
    const float* cb1 = (const float*)d_in[13];
    const float* cw2 = (const float*)d_in[14];
    float* out = (float*)d_out;

    // ws layout — ~35 MB total
    float* agg   = (float*)d_ws;                      // 5,120,000 f (zeroed)
    float* aggt  = agg + (size_t)BN * NN * HH;        // 120,000 f  (zeroed)
    int*   histI = (int*)(aggt + (size_t)BN * NN * 3);// 20,000 i   (zeroed)
    float* cnt   = (float*)(histI + NN);              // 20,000 f   (scan-written)
    int*   cursor= (int*)(cnt + NN);                  // 20,000 i   (scan-written)
    int*   rowS  = cursor + NN;                       // 400,000 i  (scatter-written)
    int*   colS  = rowS + NE;                         // 400,000 i  (scatter-written)
    ushort_t* hbf  = (ushort_t*)(colS + NE);          // 5,120,000 bf16
    ushort_t* w1p  = hbf + (size_t)BN * NN * HH;      // 32768
    ushort_t* w2p  = w1p + 32768;                     // 16384
    ushort_t* cw1p = w2p + 16384;                     // 16384
    ushort_t* nw1p = cw1p + 16384;                    // 49152
    ushort_t* nw2p = nw1p + 49152;                    // 16384

    const size_t zero_bytes =
        ((size_t)BN * NN * HH + (size_t)BN * NN * 3 + NN) * sizeof(float);
    hipMemsetAsync(d_ws, 0, zero_bytes, stream);   // agg + aggt + histI

    const int n4 = (BN * NN * HH) / 4;
    cvt_h_kernel<<<n4 / 256, 256, 0, stream>>>((const float4*)h, (uint2*)hbf, n4);
    pack_w_kernel<<<16, 256, 0, stream>>>(w1, w1p, 256);
    pack_w_kernel<<<8, 256, 0, stream>>>(w2, w2p, 128);
    pack_w_kernel<<<8, 256, 0, stream>>>(cw1, cw1p, 128);
    pack_w_kernel<<<24, 256, 0, stream>>>(nw1, nw1p, 384);
    pack_w_kernel<<<8, 256, 0, stream>>>(nw2, nw2p, 128);

    hist_kernel<<<(NE + 255) / 256, 256, 0, stream>>>(eidx, histI);
    scan_kernel<<<1, 256, 0, stream>>>(histI, cursor, cnt);
    scatter_kernel<<<(NE + 255) / 256, 256, 0, stream>>>(eidx, cursor, rowS, colS);

    dim3 eg(NE / 128, BN);
    edge_kernel<<<eg, 256, 0, stream>>>(hbf, coord, rowS, colS, w1p, w2p, cw1p,
                                        w1, b1, b2, cb1, cw2, agg, aggt);

    dim3 ng((NN + 63) / 64, BN);
    node_kernel<<<ng, 256, 0, stream>>>(hbf, h, coord, others, agg,
                                        nw1p, nw2p, nb1, nb2, aggt, cnt, out);
}